// Round 8
// baseline (610.475 us; speedup 1.0000x reference)
//
#include <hip/hip_runtime.h>

// Problem: N=C=H=W=64. n = N*H*W = 262144 samples per channel.
// ws layout:
//   [0,     32768)  S      double[64*64]   Gram accumulator
//   [32768, 33280)  rowsum double[64]
//   [33280, 49664)  T      float[64*64]    folded transform
//   [49664, 49920)  off    float[64]       folded offset

// Gram + row sums. Grid 512: (n = b>>3, hw eighth = b&7). 4 tiles of 128.
__global__ __launch_bounds__(256) void zca_gram_k(const float* __restrict__ x,
                                                  double* __restrict__ S,
                                                  double* __restrict__ rowsum) {
  __shared__ float XT[128 * 72];  // row kk (stride 72), 64 channels
  const int t = threadIdx.x;
  const int n = blockIdx.x >> 3;
  const int k0base = (blockIdx.x & 7) << 9;
  const float* xb = x + ((size_t)n << 18);
  const int cg = t >> 4, dg = t & 15;
  const int sc = t & 63, kq = t >> 6;

  double acc[4][4];
#pragma unroll
  for (int i = 0; i < 4; ++i)
#pragma unroll
    for (int j = 0; j < 4; ++j) acc[i][j] = 0.0;
  double rs[4] = {0.0, 0.0, 0.0, 0.0};

  for (int tile = 0; tile < 4; ++tile) {
    const int k0 = k0base + (tile << 7);
#pragma unroll
    for (int r = 0; r < 8; ++r) {
      const int kk = ((kq << 3) + r) << 2;
      const float4 v = *reinterpret_cast<const float4*>(xb + ((size_t)sc << 12) + k0 + kk);
      XT[(kk + 0) * 72 + sc] = v.x;
      XT[(kk + 1) * 72 + sc] = v.y;
      XT[(kk + 2) * 72 + sc] = v.z;
      XT[(kk + 3) * 72 + sc] = v.w;
    }
    __syncthreads();
    float accf[4][4];
#pragma unroll
    for (int i = 0; i < 4; ++i)
#pragma unroll
      for (int j = 0; j < 4; ++j) accf[i][j] = 0.0f;
    float rsf[4] = {0.f, 0.f, 0.f, 0.f};
#pragma unroll 2
    for (int kk = 0; kk < 128; ++kk) {
      const float4 a4 = *reinterpret_cast<const float4*>(XT + kk * 72 + (cg << 2));
      const float4 b4 = *reinterpret_cast<const float4*>(XT + kk * 72 + (dg << 2));
      const float a[4] = {a4.x, a4.y, a4.z, a4.w};
      const float b[4] = {b4.x, b4.y, b4.z, b4.w};
#pragma unroll
      for (int i = 0; i < 4; ++i) {
#pragma unroll
        for (int j = 0; j < 4; ++j) accf[i][j] = fmaf(a[i], b[j], accf[i][j]);
        rsf[i] += a[i];
      }
    }
#pragma unroll
    for (int i = 0; i < 4; ++i) {
#pragma unroll
      for (int j = 0; j < 4; ++j) acc[i][j] += (double)accf[i][j];
      rs[i] += (double)rsf[i];
    }
    __syncthreads();
  }
  const int c0 = cg << 2, d0 = dg << 2;
#pragma unroll
  for (int i = 0; i < 4; ++i)
#pragma unroll
    for (int j = 0; j < 4; ++j)
      atomicAdd(&S[(c0 + i) * 64 + d0 + j], acc[i][j]);
  if (dg == 0) {
#pragma unroll
    for (int i = 0; i < 4; ++i) atomicAdd(&rowsum[c0 + i], rs[i]);
  }
}

// round-robin tournament pairing: 32 disjoint pairs covering all 64 indices.
__device__ __forceinline__ void zca_sched(int j, int r, int& p, int& q) {
  if (j == 0) {
    p = 0;
    int a = 62 + r; if (a >= 63) a -= 63;
    q = 1 + a;
  } else {
    int a = j - 1 + r;  if (a >= 63) a -= 63;
    int b = 62 - j + r; if (b >= 63) b -= 63;
    p = 1 + a;
    q = 1 + b;
  }
}

// DPP quad_perm fetches — pure VALU, no LDS pipe.
__device__ __forceinline__ float zca_dpp_xor1(float v) {  // [1,0,3,2]
  const int vi = __builtin_bit_cast(int, v);
  const int pi = __builtin_amdgcn_update_dpp(vi, vi, 0xB1, 0xF, 0xF, true);
  return __builtin_bit_cast(float, pi);
}
__device__ __forceinline__ float zca_dpp_xor2(float v) {  // [2,3,0,1]
  const int vi = __builtin_bit_cast(int, v);
  const int pi = __builtin_amdgcn_update_dpp(vi, vi, 0x4E, 0xF, 0xF, true);
  return __builtin_bit_cast(float, pi);
}

// Single block. One-sided (Hestenes) Jacobi on columns of G = M0, f32,
// ONE WAVE, zero barriers in the loop. Each 32-pair tournament round is
// split into two 16-pair chunks on disjoint columns (rotations commute ->
// bitwise-identical result). 4 lanes/pair, 16 elems/lane. All reads for
// BOTH chunks issue up-front; compute+write of chunk A overlaps chunk B's
// LDS read latency (counted lgkmcnt by the compiler); chunk B then
// computes with its data already resident. Pair-reduce = 2 intra-quad DPP
// adds (commutative -> identical in all 4 lanes -> consistent angles).
// Incremental norms in LDS; exact lambda recomputed at the end.
// No V matrix: at convergence G = M0*V, so v_i = G[:,i]/||G[:,i]||.
__global__ __launch_bounds__(256) void zca_solve_k(const double* __restrict__ S,
                                                   const double* __restrict__ rowsum,
                                                   const float* __restrict__ weight,
                                                   const float* __restrict__ bias,
                                                   float* __restrict__ T,
                                                   float* __restrict__ offv) {
  __shared__ __align__(16) float G[64 * 68];  // column-major, col stride 68
  __shared__ float norms[64];                 // running squared col norms
  __shared__ float lam[64];
  __shared__ float msd[64];                   // mu/sig (f32)
  __shared__ float isg[64];                   // 1/sig (f32)
  __shared__ double mu[64], sig[64];
  __shared__ float wk2[64];                   // active * lam^(-5/2)
  __shared__ int idxs[64];
  const int t = threadIdx.x;
  const double n = 262144.0;

  if (t < 64) {
    const double m = rowsum[t] / n;
    const double var = (S[t * 64 + t] - n * m * m) / (n - 1.0);
    mu[t] = m;
    sig[t] = sqrt(var + 1e-5);
    msd[t] = (float)(m / sig[t]);
    isg[t] = (float)(1.0 / sig[t]);
  }
  __syncthreads();
  for (int e = t; e < 4096; e += 256) {
    const int col = e >> 6, row = e & 63;
    double v = (S[row * 64 + col] - n * mu[row] * mu[col]) / (n * sig[row] * sig[col]);
    if (row == col) v += 1e-5;
    G[col * 68 + row] = (float)v;
  }
  __syncthreads();
  if (t < 64) {  // initial squared column norms
    float s = 0.0f;
#pragma unroll
    for (int j4 = 0; j4 < 16; ++j4) {
      const float4 v = *reinterpret_cast<const float4*>(G + t * 68 + (j4 << 2));
      s = fmaf(v.x, v.x, s); s = fmaf(v.y, v.y, s);
      s = fmaf(v.z, v.z, s); s = fmaf(v.w, v.w, s);
    }
    norms[t] = s;
  }
  __syncthreads();

  if (t < 64) {  // ---- single-wave Jacobi: A/B chunk-pipelined rounds ----
    const int pr = t >> 2;       // pair index within chunk (0..15)
    const int sub = t & 3;
    const int o = sub << 4;      // 16 floats per lane
    for (int sweep = 0; sweep < 7; ++sweep) {
      int anyflag = 0;
      for (int r = 0; r < 63; ++r) {
        int pA, qA, pB, qB;
        zca_sched(pr, r, pA, qA);
        zca_sched(pr + 16, r, pB, qB);
        float* GpA = G + pA * 68 + o;
        float* GqA = G + qA * 68 + o;
        float* GpB = G + pB * 68 + o;
        float* GqB = G + qB * 68 + o;
        // all LDS reads up-front: norms then both chunks' column slices
        const float napA = norms[pA], naqA = norms[qA];
        const float napB = norms[pB], naqB = norms[qB];
        float4 PA[4], QA[4], PB[4], QB[4];
#pragma unroll
        for (int i = 0; i < 4; ++i) PA[i] = *reinterpret_cast<float4*>(GpA + (i << 2));
#pragma unroll
        for (int i = 0; i < 4; ++i) QA[i] = *reinterpret_cast<float4*>(GqA + (i << 2));
#pragma unroll
        for (int i = 0; i < 4; ++i) PB[i] = *reinterpret_cast<float4*>(GpB + (i << 2));
#pragma unroll
        for (int i = 0; i < 4; ++i) QB[i] = *reinterpret_cast<float4*>(GqB + (i << 2));
        // ---- chunk A (waits only for its own reads) ----
        {
          float s0 = 0.f, s1 = 0.f, s2 = 0.f, s3 = 0.f;
#pragma unroll
          for (int i = 0; i < 4; ++i) {
            s0 = fmaf(PA[i].x, QA[i].x, s0);
            s1 = fmaf(PA[i].y, QA[i].y, s1);
            s2 = fmaf(PA[i].z, QA[i].z, s2);
            s3 = fmaf(PA[i].w, QA[i].w, s3);
          }
          float apq = (s0 + s1) + (s2 + s3);
          apq += zca_dpp_xor1(apq);
          apq += zca_dpp_xor2(apq);
          if (apq * apq > 1e-10f * napA * naqA) {
            anyflag = 1;
            const float tau = (naqA - napA) / (2.0f * apq);
            const float tt = (tau >= 0.0f ? 1.0f : -1.0f) / (fabsf(tau) + sqrtf(1.0f + tau * tau));
            const float c = 1.0f / sqrtf(1.0f + tt * tt);
            const float s = tt * c;
#pragma unroll
            for (int i = 0; i < 4; ++i) {
              float4 np, nq;
              np.x = c * PA[i].x - s * QA[i].x; np.y = c * PA[i].y - s * QA[i].y;
              np.z = c * PA[i].z - s * QA[i].z; np.w = c * PA[i].w - s * QA[i].w;
              nq.x = s * PA[i].x + c * QA[i].x; nq.y = s * PA[i].y + c * QA[i].y;
              nq.z = s * PA[i].z + c * QA[i].z; nq.w = s * PA[i].w + c * QA[i].w;
              *reinterpret_cast<float4*>(GpA + (i << 2)) = np;
              *reinterpret_cast<float4*>(GqA + (i << 2)) = nq;
            }
            if (sub == 0) norms[pA] = fmaf(-tt, apq, napA);
            if (sub == 1) norms[qA] = fmaf(tt, apq, naqA);
          }
        }
        // ---- chunk B (reads completed during A's compute) ----
        {
          float s0 = 0.f, s1 = 0.f, s2 = 0.f, s3 = 0.f;
#pragma unroll
          for (int i = 0; i < 4; ++i) {
            s0 = fmaf(PB[i].x, QB[i].x, s0);
            s1 = fmaf(PB[i].y, QB[i].y, s1);
            s2 = fmaf(PB[i].z, QB[i].z, s2);
            s3 = fmaf(PB[i].w, QB[i].w, s3);
          }
          float apq = (s0 + s1) + (s2 + s3);
          apq += zca_dpp_xor1(apq);
          apq += zca_dpp_xor2(apq);
          if (apq * apq > 1e-10f * napB * naqB) {
            anyflag = 1;
            const float tau = (naqB - napB) / (2.0f * apq);
            const float tt = (tau >= 0.0f ? 1.0f : -1.0f) / (fabsf(tau) + sqrtf(1.0f + tau * tau));
            const float c = 1.0f / sqrtf(1.0f + tt * tt);
            const float s = tt * c;
#pragma unroll
            for (int i = 0; i < 4; ++i) {
              float4 np, nq;
              np.x = c * PB[i].x - s * QB[i].x; np.y = c * PB[i].y - s * QB[i].y;
              np.z = c * PB[i].z - s * QB[i].z; np.w = c * PB[i].w - s * QB[i].w;
              nq.x = s * PB[i].x + c * QB[i].x; nq.y = s * PB[i].y + c * QB[i].y;
              nq.z = s * PB[i].z + c * QB[i].z; nq.w = s * PB[i].w + c * QB[i].w;
              *reinterpret_cast<float4*>(GpB + (i << 2)) = np;
              *reinterpret_cast<float4*>(GqB + (i << 2)) = nq;
            }
            if (sub == 0) norms[pB] = fmaf(-tt, apq, napB);
            if (sub == 1) norms[qB] = fmaf(tt, apq, naqB);
          }
        }
        __builtin_amdgcn_wave_barrier();  // pin LDS program order across rounds
      }
      if (!__any(anyflag)) break;
    }
  }
  __syncthreads();

  // eigenvalues = exact column norms of converged G (G[:,i] = lam_i * v_i)
  if (t < 64) {
    float s = 0.0f;
#pragma unroll
    for (int j4 = 0; j4 < 16; ++j4) {
      const float4 v = *reinterpret_cast<const float4*>(G + t * 68 + (j4 << 2));
      s = fmaf(v.x, v.x, s); s = fmaf(v.y, v.y, s);
      s = fmaf(v.z, v.z, s); s = fmaf(v.w, v.w, s);
    }
    lam[t] = sqrtf(s);
  }
  __syncthreads();
  if (t < 64) {
    const float e = lam[t];
    int rank = 0;
    for (int j = 0; j < 64; ++j) {
      const float ej = lam[j];
      if (ej > e || (ej == e && j < t)) ++rank;
    }
    idxs[rank] = t;
  }
  __syncthreads();
  if (t == 0) {
    double total = 0.0;
    for (int j = 0; j < 64; ++j) total += (double)lam[j];
    double cum = 0.0;
    bool done = false;
    for (int k = 0; k < 64; ++k) {
      const double l = (double)lam[idxs[k]];
      cum += l;
      double w = 0.0;
      if (k < 32 && !done) w = 1.0 / (sqrt(l) * l * l);  // lam^(-1/2) / lam^2
      if (cum / total >= 0.95) done = true;
      wk2[k] = (float)w;
    }
  }
  __syncthreads();
  // Wxr[c][d] = sum_k wk2[k] * G[c,idx_k] * G[d,idx_k]; fold into T and off.
  {
    const int c = t >> 2, db = (t & 3) << 4;
    float accf[16];
#pragma unroll
    for (int d = 0; d < 16; ++d) accf[d] = 0.0f;
    for (int k = 0; k < 32; ++k) {
      const int sk = idxs[k];
      const float vc = wk2[k] * G[sk * 68 + c];
      const float* gcol = G + sk * 68 + db;
#pragma unroll
      for (int d4 = 0; d4 < 4; ++d4) {
        const float4 v = *reinterpret_cast<const float4*>(gcol + (d4 << 2));
        accf[d4 * 4 + 0] = fmaf(vc, v.x, accf[d4 * 4 + 0]);
        accf[d4 * 4 + 1] = fmaf(vc, v.y, accf[d4 * 4 + 1]);
        accf[d4 * 4 + 2] = fmaf(vc, v.z, accf[d4 * 4 + 2]);
        accf[d4 * 4 + 3] = fmaf(vc, v.w, accf[d4 * 4 + 3]);
      }
    }
    const float wc = weight[c];
    float po = 0.0f;
#pragma unroll
    for (int d = 0; d < 16; ++d) {
      T[c * 64 + db + d] = wc * accf[d] * isg[db + d];
      po = fmaf(accf[d], msd[db + d], po);
    }
    po += __shfl_xor(po, 1);
    po += __shfl_xor(po, 2);
    if ((t & 3) == 0) offv[c] = bias[c] - wc * po;
  }
}

// out[n,c,k] = sum_d T[c][d]*x[n,d,k] + off[c].
// Grid 512: (n = b>>3, 512 k per block, 2 positions per thread).
__global__ __launch_bounds__(256) void zca_apply_k(const float* __restrict__ x,
                                                   const float* __restrict__ T,
                                                   const float* __restrict__ offv,
                                                   float* __restrict__ out) {
  __shared__ __align__(16) float4 Tl4[64 * 16];  // Tl4[c*16 + d4]
  __shared__ float offl[64];
  const int t = threadIdx.x;
  for (int e = t; e < 1024; e += 256) Tl4[e] = reinterpret_cast<const float4*>(T)[e];
  if (t < 64) offl[t] = offv[t];
  __syncthreads();
  const int n = blockIdx.x >> 3;
  const int k0 = ((blockIdx.x & 7) << 9) + (t << 1);
  const float* xb = x + ((size_t)n << 18) + k0;
  float2 acc[64];
#pragma unroll
  for (int c = 0; c < 64; ++c) { acc[c].x = offl[c]; acc[c].y = offl[c]; }
  float2 xv[4];
#pragma unroll
  for (int dd = 0; dd < 4; ++dd)
    xv[dd] = *reinterpret_cast<const float2*>(xb + ((size_t)dd << 12));
  for (int d4 = 0; d4 < 16; ++d4) {
    float2 xn[4];
    if (d4 < 15) {
#pragma unroll
      for (int dd = 0; dd < 4; ++dd)
        xn[dd] = *reinterpret_cast<const float2*>(xb + ((size_t)((d4 + 1) * 4 + dd) << 12));
    }
#pragma unroll
    for (int c = 0; c < 64; ++c) {
      const float4 tv = Tl4[(c << 4) + d4];
      acc[c].x = fmaf(tv.x, xv[0].x, acc[c].x); acc[c].y = fmaf(tv.x, xv[0].y, acc[c].y);
      acc[c].x = fmaf(tv.y, xv[1].x, acc[c].x); acc[c].y = fmaf(tv.y, xv[1].y, acc[c].y);
      acc[c].x = fmaf(tv.z, xv[2].x, acc[c].x); acc[c].y = fmaf(tv.z, xv[2].y, acc[c].y);
      acc[c].x = fmaf(tv.w, xv[3].x, acc[c].x); acc[c].y = fmaf(tv.w, xv[3].y, acc[c].y);
    }
#pragma unroll
    for (int dd = 0; dd < 4; ++dd) xv[dd] = xn[dd];
  }
  float* ob = out + ((size_t)n << 18) + k0;
#pragma unroll
  for (int c = 0; c < 64; ++c)
    *reinterpret_cast<float2*>(ob + ((size_t)c << 12)) = acc[c];
}

extern "C" void kernel_launch(void* const* d_in, const int* in_sizes, int n_in,
                              void* d_out, int out_size, void* d_ws, size_t ws_size,
                              hipStream_t stream) {
  const float* x = (const float*)d_in[0];
  const float* weight = (const float*)d_in[1];
  const float* bias = (const float*)d_in[2];
  float* out = (float*)d_out;
  char* ws = (char*)d_ws;
  double* S = (double*)ws;
  double* rowsum = (double*)(ws + 32768);
  float* T = (float*)(ws + 33280);
  float* offv = (float*)(ws + 49664);

  hipMemsetAsync(S, 0, 33280, stream);  // S + rowsum (graph-capturable)
  hipLaunchKernelGGL(zca_gram_k, dim3(512), dim3(256), 0, stream, x, S, rowsum);
  hipLaunchKernelGGL(zca_solve_k, dim3(1), dim3(256), 0, stream, S, rowsum, weight, bias, T, offv);
  hipLaunchKernelGGL(zca_apply_k, dim3(512), dim3(256), 0, stream, x, T, offv, out);
}

// Round 10
// 509.918 us; speedup vs baseline: 1.1972x; 1.1972x over previous
//
#include <hip/hip_runtime.h>

// Problem: N=C=H=W=64. n = N*H*W = 262144 samples per channel.
// ws layout:
//   [0,     32768)  S      double[64*64]   Gram accumulator
//   [32768, 33280)  rowsum double[64]
//   [33280, 49664)  T      float[64*64]    folded transform
//   [49664, 49920)  off    float[64]       folded offset

// Gram + row sums. Grid 512: (n = b>>3, hw eighth = b&7). 4 tiles of 128.
// Tile staged TRANSPOSED: XT[kk][c] so both operand fragments are b128 reads.
__global__ __launch_bounds__(256) void zca_gram_k(const float* __restrict__ x,
                                                  double* __restrict__ S,
                                                  double* __restrict__ rowsum) {
  __shared__ float XT[128 * 72];  // row kk (stride 72), 64 channels
  const int t = threadIdx.x;
  const int n = blockIdx.x >> 3;
  const int k0base = (blockIdx.x & 7) << 9;
  const float* xb = x + ((size_t)n << 18);
  const int cg = t >> 4, dg = t & 15;
  const int sc = t & 63, kq = t >> 6;

  double acc[4][4];
#pragma unroll
  for (int i = 0; i < 4; ++i)
#pragma unroll
    for (int j = 0; j < 4; ++j) acc[i][j] = 0.0;
  double rs[4] = {0.0, 0.0, 0.0, 0.0};

  for (int tile = 0; tile < 4; ++tile) {
    const int k0 = k0base + (tile << 7);
#pragma unroll
    for (int r = 0; r < 8; ++r) {
      const int kk = ((kq << 3) + r) << 2;
      const float4 v = *reinterpret_cast<const float4*>(xb + ((size_t)sc << 12) + k0 + kk);
      XT[(kk + 0) * 72 + sc] = v.x;
      XT[(kk + 1) * 72 + sc] = v.y;
      XT[(kk + 2) * 72 + sc] = v.z;
      XT[(kk + 3) * 72 + sc] = v.w;
    }
    __syncthreads();
    float accf[4][4];
#pragma unroll
    for (int i = 0; i < 4; ++i)
#pragma unroll
      for (int j = 0; j < 4; ++j) accf[i][j] = 0.0f;
    float rsf[4] = {0.f, 0.f, 0.f, 0.f};
#pragma unroll 2
    for (int kk = 0; kk < 128; ++kk) {
      const float4 a4 = *reinterpret_cast<const float4*>(XT + kk * 72 + (cg << 2));
      const float4 b4 = *reinterpret_cast<const float4*>(XT + kk * 72 + (dg << 2));
      const float a[4] = {a4.x, a4.y, a4.z, a4.w};
      const float b[4] = {b4.x, b4.y, b4.z, b4.w};
#pragma unroll
      for (int i = 0; i < 4; ++i) {
#pragma unroll
        for (int j = 0; j < 4; ++j) accf[i][j] = fmaf(a[i], b[j], accf[i][j]);
        rsf[i] += a[i];
      }
    }
#pragma unroll
    for (int i = 0; i < 4; ++i) {
#pragma unroll
      for (int j = 0; j < 4; ++j) acc[i][j] += (double)accf[i][j];
      rs[i] += (double)rsf[i];
    }
    __syncthreads();
  }
  const int c0 = cg << 2, d0 = dg << 2;
#pragma unroll
  for (int i = 0; i < 4; ++i)
#pragma unroll
    for (int j = 0; j < 4; ++j)
      atomicAdd(&S[(c0 + i) * 64 + d0 + j], acc[i][j]);
  if (dg == 0) {
#pragma unroll
    for (int i = 0; i < 4; ++i) atomicAdd(&rowsum[c0 + i], rs[i]);
  }
}

// round-robin tournament pairing: 32 disjoint pairs covering all 64 indices.
__device__ __forceinline__ void zca_sched(int j, int r, int& p, int& q) {
  if (j == 0) {
    p = 0;
    int a = 62 + r; if (a >= 63) a -= 63;
    q = 1 + a;
  } else {
    int a = j - 1 + r;  if (a >= 63) a -= 63;
    int b = 62 - j + r; if (b >= 63) b -= 63;
    p = 1 + a;
    q = 1 + b;
  }
}

// Single block. One-sided (Hestenes) Jacobi on columns of G = M0, f32,
// ONE WAVE (2 lanes/pair, 32 elems/lane), zero barriers in the loop —
// r4's structure (664 ns/round, fastest measured) with r7's validated
// numerics: skip threshold 1e-10 rel (passes at absmax 0.0156; 1e-8
// measured FAIL at 0.070), sweep cap 7 (validated).
// No V matrix: at convergence G = M0*V, so v_i = G[:,i]/||G[:,i]||.
__global__ __launch_bounds__(256) void zca_solve_k(const double* __restrict__ S,
                                                   const double* __restrict__ rowsum,
                                                   const float* __restrict__ weight,
                                                   const float* __restrict__ bias,
                                                   float* __restrict__ T,
                                                   float* __restrict__ offv) {
  __shared__ __align__(16) float G[64 * 68];  // column-major, col stride 68
  __shared__ float norms[64];                 // running squared col norms
  __shared__ float lam[64];
  __shared__ float msd[64];                   // mu/sig (f32)
  __shared__ float isg[64];                   // 1/sig (f32)
  __shared__ double mu[64], sig[64];
  __shared__ float wk2[64];                   // active * lam^(-5/2)
  __shared__ int idxs[64];
  const int t = threadIdx.x;
  const double n = 262144.0;

  if (t < 64) {
    const double m = rowsum[t] / n;
    const double var = (S[t * 64 + t] - n * m * m) / (n - 1.0);
    mu[t] = m;
    sig[t] = sqrt(var + 1e-5);
    msd[t] = (float)(m / sig[t]);
    isg[t] = (float)(1.0 / sig[t]);
  }
  __syncthreads();
  for (int e = t; e < 4096; e += 256) {
    const int col = e >> 6, row = e & 63;
    double v = (S[row * 64 + col] - n * mu[row] * mu[col]) / (n * sig[row] * sig[col]);
    if (row == col) v += 1e-5;
    G[col * 68 + row] = (float)v;
  }
  __syncthreads();
  if (t < 64) {  // initial squared column norms
    float s = 0.0f;
#pragma unroll
    for (int j4 = 0; j4 < 16; ++j4) {
      const float4 v = *reinterpret_cast<const float4*>(G + t * 68 + (j4 << 2));
      s = fmaf(v.x, v.x, s); s = fmaf(v.y, v.y, s);
      s = fmaf(v.z, v.z, s); s = fmaf(v.w, v.w, s);
    }
    norms[t] = s;
  }
  __syncthreads();

  if (t < 64) {  // ---- single-wave Jacobi sweep loop, zero barriers ----
    const int g = t >> 1;
    const int o = (t & 1) << 5;  // 32 elements per lane
    for (int sweep = 0; sweep < 7; ++sweep) {
      int anyflag = 0;
      for (int r = 0; r < 63; ++r) {
        int p, q;
        zca_sched(g, r, p, q);
        float* Gp = G + p * 68 + o;
        float* Gq = G + q * 68 + o;
        float4 P[8], Q[8];
#pragma unroll
        for (int i = 0; i < 8; ++i) P[i] = *reinterpret_cast<float4*>(Gp + (i << 2));
#pragma unroll
        for (int i = 0; i < 8; ++i) Q[i] = *reinterpret_cast<float4*>(Gq + (i << 2));
        float s0 = 0.f, s1 = 0.f, s2 = 0.f, s3 = 0.f;
#pragma unroll
        for (int i = 0; i < 8; ++i) {
          s0 = fmaf(P[i].x, Q[i].x, s0);
          s1 = fmaf(P[i].y, Q[i].y, s1);
          s2 = fmaf(P[i].z, Q[i].z, s2);
          s3 = fmaf(P[i].w, Q[i].w, s3);
        }
        float apq = (s0 + s1) + (s2 + s3);
        apq += __shfl_xor(apq, 1);
        const float app = norms[p], aqq = norms[q];
        if (apq * apq > 1e-10f * app * aqq) {
          anyflag = 1;
          const float tau = (aqq - app) / (2.0f * apq);
          const float tt = (tau >= 0.0f ? 1.0f : -1.0f) / (fabsf(tau) + sqrtf(1.0f + tau * tau));
          const float c = 1.0f / sqrtf(1.0f + tt * tt);
          const float s = tt * c;
#pragma unroll
          for (int i = 0; i < 8; ++i) {
            float4 np, nq;
            np.x = c * P[i].x - s * Q[i].x; np.y = c * P[i].y - s * Q[i].y;
            np.z = c * P[i].z - s * Q[i].z; np.w = c * P[i].w - s * Q[i].w;
            nq.x = s * P[i].x + c * Q[i].x; nq.y = s * P[i].y + c * Q[i].y;
            nq.z = s * P[i].z + c * Q[i].z; nq.w = s * P[i].w + c * Q[i].w;
            *reinterpret_cast<float4*>(Gp + (i << 2)) = np;
            *reinterpret_cast<float4*>(Gq + (i << 2)) = nq;
          }
          // lane0 of pair owns norms[p] (-= tt*apq), lane1 owns norms[q]
          if ((t & 1) == 0) norms[p] = fmaf(-tt, apq, app);
          else              norms[q] = fmaf(tt, apq, aqq);
        }
        __builtin_amdgcn_wave_barrier();  // pin LDS program order across rounds
      }
      if (!__any(anyflag)) break;
    }
  }
  __syncthreads();

  // eigenvalues = exact column norms of converged G (G[:,i] = lam_i * v_i)
  if (t < 64) {
    float s = 0.0f;
#pragma unroll
    for (int j4 = 0; j4 < 16; ++j4) {
      const float4 v = *reinterpret_cast<const float4*>(G + t * 68 + (j4 << 2));
      s = fmaf(v.x, v.x, s); s = fmaf(v.y, v.y, s);
      s = fmaf(v.z, v.z, s); s = fmaf(v.w, v.w, s);
    }
    lam[t] = sqrtf(s);
  }
  __syncthreads();
  if (t < 64) {
    const float e = lam[t];
    int rank = 0;
    for (int j = 0; j < 64; ++j) {
      const float ej = lam[j];
      if (ej > e || (ej == e && j < t)) ++rank;
    }
    idxs[rank] = t;
  }
  __syncthreads();
  if (t == 0) {
    double total = 0.0;
    for (int j = 0; j < 64; ++j) total += (double)lam[j];
    double cum = 0.0;
    bool done = false;
    for (int k = 0; k < 64; ++k) {
      const double l = (double)lam[idxs[k]];
      cum += l;
      double w = 0.0;
      if (k < 32 && !done) w = 1.0 / (sqrt(l) * l * l);  // lam^(-1/2) / lam^2
      if (cum / total >= 0.95) done = true;
      wk2[k] = (float)w;
    }
  }
  __syncthreads();
  // Wxr[c][d] = sum_k wk2[k] * G[c,idx_k] * G[d,idx_k]; fold into T and off.
  {
    const int c = t >> 2, db = (t & 3) << 4;
    float accf[16];
#pragma unroll
    for (int d = 0; d < 16; ++d) accf[d] = 0.0f;
    for (int k = 0; k < 32; ++k) {
      const int sk = idxs[k];
      const float vc = wk2[k] * G[sk * 68 + c];
      const float* gcol = G + sk * 68 + db;
#pragma unroll
      for (int d4 = 0; d4 < 4; ++d4) {
        const float4 v = *reinterpret_cast<const float4*>(gcol + (d4 << 2));
        accf[d4 * 4 + 0] = fmaf(vc, v.x, accf[d4 * 4 + 0]);
        accf[d4 * 4 + 1] = fmaf(vc, v.y, accf[d4 * 4 + 1]);
        accf[d4 * 4 + 2] = fmaf(vc, v.z, accf[d4 * 4 + 2]);
        accf[d4 * 4 + 3] = fmaf(vc, v.w, accf[d4 * 4 + 3]);
      }
    }
    const float wc = weight[c];
    float po = 0.0f;
#pragma unroll
    for (int d = 0; d < 16; ++d) {
      T[c * 64 + db + d] = wc * accf[d] * isg[db + d];
      po = fmaf(accf[d], msd[db + d], po);
    }
    po += __shfl_xor(po, 1);
    po += __shfl_xor(po, 2);
    if ((t & 3) == 0) offv[c] = bias[c] - wc * po;
  }
}

// out[n,c,k] = sum_d T[c][d]*x[n,d,k] + off[c].
// Grid 512: (n = b>>3, 512 k per block, 2 positions per thread).
// T/off reads are loop-uniform -> scalar s_load path (SMEM pipe, K$/L2-hot
// 16KB): no LDS at all, no staging barrier, DS pipe freed.
__global__ __launch_bounds__(256) void zca_apply_k(const float* __restrict__ x,
                                                   const float* __restrict__ T,
                                                   const float* __restrict__ offv,
                                                   float* __restrict__ out) {
  const int t = threadIdx.x;
  const int n = blockIdx.x >> 3;
  const int k0 = ((blockIdx.x & 7) << 9) + (t << 1);
  const float* xb = x + ((size_t)n << 18) + k0;
  const float4* __restrict__ T4 = reinterpret_cast<const float4*>(T);
  float2 acc[64];
#pragma unroll
  for (int c = 0; c < 64; ++c) {
    const float o = offv[c];  // uniform -> s_load
    acc[c].x = o; acc[c].y = o;
  }
  float2 xv[4];
#pragma unroll
  for (int dd = 0; dd < 4; ++dd)
    xv[dd] = *reinterpret_cast<const float2*>(xb + ((size_t)dd << 12));
  for (int d4 = 0; d4 < 16; ++d4) {
    float2 xn[4];
    if (d4 < 15) {
#pragma unroll
      for (int dd = 0; dd < 4; ++dd)
        xn[dd] = *reinterpret_cast<const float2*>(xb + ((size_t)((d4 + 1) * 4 + dd) << 12));
    }
#pragma unroll
    for (int c = 0; c < 64; ++c) {
      const float4 tv = T4[(c << 4) + d4];  // uniform -> s_load_dwordx4
      acc[c].x = fmaf(tv.x, xv[0].x, acc[c].x); acc[c].y = fmaf(tv.x, xv[0].y, acc[c].y);
      acc[c].x = fmaf(tv.y, xv[1].x, acc[c].x); acc[c].y = fmaf(tv.y, xv[1].y, acc[c].y);
      acc[c].x = fmaf(tv.z, xv[2].x, acc[c].x); acc[c].y = fmaf(tv.z, xv[2].y, acc[c].y);
      acc[c].x = fmaf(tv.w, xv[3].x, acc[c].x); acc[c].y = fmaf(tv.w, xv[3].y, acc[c].y);
    }
#pragma unroll
    for (int dd = 0; dd < 4; ++dd) xv[dd] = xn[dd];
  }
  float* ob = out + ((size_t)n << 18) + k0;
#pragma unroll
  for (int c = 0; c < 64; ++c)
    *reinterpret_cast<float2*>(ob + ((size_t)c << 12)) = acc[c];
}

extern "C" void kernel_launch(void* const* d_in, const int* in_sizes, int n_in,
                              void* d_out, int out_size, void* d_ws, size_t ws_size,
                              hipStream_t stream) {
  const float* x = (const float*)d_in[0];
  const float* weight = (const float*)d_in[1];
  const float* bias = (const float*)d_in[2];
  float* out = (float*)d_out;
  char* ws = (char*)d_ws;
  double* S = (double*)ws;
  double* rowsum = (double*)(ws + 32768);
  float* T = (float*)(ws + 33280);
  float* offv = (float*)(ws + 49664);

  hipMemsetAsync(S, 0, 33280, stream);  // S + rowsum (graph-capturable)
  hipLaunchKernelGGL(zca_gram_k, dim3(512), dim3(256), 0, stream, x, S, rowsum);
  hipLaunchKernelGGL(zca_solve_k, dim3(1), dim3(256), 0, stream, S, rowsum, weight, bias, T, offv);
  hipLaunchKernelGGL(zca_apply_k, dim3(512), dim3(256), 0, stream, x, T, offv, out);
}

// Round 11
// 462.110 us; speedup vs baseline: 1.3211x; 1.1035x over previous
//
#include <hip/hip_runtime.h>

// Problem: N=C=H=W=64. n = N*H*W = 262144 samples per channel.
// ws layout:
//   [0,     32768)  S      double[64*64]   Gram accumulator
//   [32768, 33280)  rowsum double[64]
//   [33280, 49664)  T      float[64*64]    folded transform
//   [49664, 49920)  off    float[64]       folded offset

// Gram + row sums, v2: 8x8 register blocking. Grid 256: (n = b>>2, k-quarter
// = b&3, 1024 k each), 8 tiles of 128 k. Per tile: stage XT[128][72]
// transposed, then each of the 4 waves owns a 32-k slice and computes the
// full 64x64 Gram over it (lane = 8x8 subtile; reads = 4 b128 per k per
// lane, 8-way broadcast, 2-way bank alias = free). reads/FMA = 0.25 vs 0.5
// for 4x4 — halves the DS-issue bound. f32 accumulation throughout (merged
// error ~4e-6 relative — far below eigen-gaps); per-wave partials merged in
// LDS -> one f64 atomicAdd set per block (1M atomics total, halved chains).
__global__ __launch_bounds__(256) void zca_gram_k(const float* __restrict__ x,
                                                  double* __restrict__ S,
                                                  double* __restrict__ rowsum) {
  __shared__ __align__(16) float buf[16384];  // phase1: XT[128][72]; phase2: 4x4096 partials
  __shared__ float rsbuf[256];
  const int t = threadIdx.x;
  const int n = blockIdx.x >> 2;
  const int k0base = (blockIdx.x & 3) << 10;
  const float* xb = x + ((size_t)n << 18);
  const int g = t >> 6;            // wave = k-group
  const int tt = t & 63;
  const int r0 = (tt >> 3) << 3;   // 8 output rows
  const int c0 = (tt & 7) << 3;    // 8 output cols

  float acc[8][8];
#pragma unroll
  for (int i = 0; i < 8; ++i)
#pragma unroll
    for (int j = 0; j < 8; ++j) acc[i][j] = 0.0f;
  float rs[8];
#pragma unroll
  for (int i = 0; i < 8; ++i) rs[i] = 0.0f;

  for (int tile = 0; tile < 8; ++tile) {
    const int k0 = k0base + (tile << 7);
#pragma unroll
    for (int r = 0; r < 8; ++r) {
      const int idx4 = t + (r << 8);
      const int c = idx4 >> 5;
      const int kk = (idx4 & 31) << 2;
      const float4 v = *reinterpret_cast<const float4*>(xb + ((size_t)c << 12) + k0 + kk);
      buf[(kk + 0) * 72 + c] = v.x;
      buf[(kk + 1) * 72 + c] = v.y;
      buf[(kk + 2) * 72 + c] = v.z;
      buf[(kk + 3) * 72 + c] = v.w;
    }
    __syncthreads();
    const int kbeg = g << 5;
#pragma unroll 2
    for (int kk = kbeg; kk < kbeg + 32; ++kk) {
      const float* row = buf + kk * 72;
      const float4 a0 = *reinterpret_cast<const float4*>(row + r0);
      const float4 a1 = *reinterpret_cast<const float4*>(row + r0 + 4);
      const float4 b0 = *reinterpret_cast<const float4*>(row + c0);
      const float4 b1 = *reinterpret_cast<const float4*>(row + c0 + 4);
      const float a[8] = {a0.x, a0.y, a0.z, a0.w, a1.x, a1.y, a1.z, a1.w};
      const float b[8] = {b0.x, b0.y, b0.z, b0.w, b1.x, b1.y, b1.z, b1.w};
#pragma unroll
      for (int i = 0; i < 8; ++i) {
#pragma unroll
        for (int j = 0; j < 8; ++j) acc[i][j] = fmaf(a[i], b[j], acc[i][j]);
        rs[i] += a[i];
      }
    }
    __syncthreads();
  }
  // merge: per-wave partial grams through LDS (buf is spent), then one
  // f64 atomicAdd set per block.
#pragma unroll
  for (int i = 0; i < 8; ++i)
#pragma unroll
    for (int j = 0; j < 8; ++j)
      buf[(g << 12) + (r0 + i) * 64 + c0 + j] = acc[i][j];
  if ((tt & 7) == 0) {
#pragma unroll
    for (int i = 0; i < 8; ++i) rsbuf[(g << 6) + r0 + i] = rs[i];
  }
  __syncthreads();
  for (int e = t; e < 4096; e += 256) {
    const float s = (buf[e] + buf[4096 + e]) + (buf[8192 + e] + buf[12288 + e]);
    atomicAdd(&S[e], (double)s);
  }
  if (t < 64) {
    const float s = (rsbuf[t] + rsbuf[64 + t]) + (rsbuf[128 + t] + rsbuf[192 + t]);
    atomicAdd(&rowsum[t], (double)s);
  }
}

// round-robin tournament pairing: 32 disjoint pairs covering all 64 indices.
__device__ __forceinline__ void zca_sched(int j, int r, int& p, int& q) {
  if (j == 0) {
    p = 0;
    int a = 62 + r; if (a >= 63) a -= 63;
    q = 1 + a;
  } else {
    int a = j - 1 + r;  if (a >= 63) a -= 63;
    int b = 62 - j + r; if (b >= 63) b -= 63;
    p = 1 + a;
    q = 1 + b;
  }
}

// Single block. One-sided (Hestenes) Jacobi on columns of G = M0, f32,
// ONE WAVE (2 lanes/pair, 32 elems/lane), zero barriers in the loop —
// r4's structure with r7/r10's validated numerics: skip threshold 1e-10
// rel (1e-8 measured FAIL), sweep cap 7 (validated). UNCHANGED from r10.
__global__ __launch_bounds__(256) void zca_solve_k(const double* __restrict__ S,
                                                   const double* __restrict__ rowsum,
                                                   const float* __restrict__ weight,
                                                   const float* __restrict__ bias,
                                                   float* __restrict__ T,
                                                   float* __restrict__ offv) {
  __shared__ __align__(16) float G[64 * 68];  // column-major, col stride 68
  __shared__ float norms[64];                 // running squared col norms
  __shared__ float lam[64];
  __shared__ float msd[64];                   // mu/sig (f32)
  __shared__ float isg[64];                   // 1/sig (f32)
  __shared__ double mu[64], sig[64];
  __shared__ float wk2[64];                   // active * lam^(-5/2)
  __shared__ int idxs[64];
  const int t = threadIdx.x;
  const double n = 262144.0;

  if (t < 64) {
    const double m = rowsum[t] / n;
    const double var = (S[t * 64 + t] - n * m * m) / (n - 1.0);
    mu[t] = m;
    sig[t] = sqrt(var + 1e-5);
    msd[t] = (float)(m / sig[t]);
    isg[t] = (float)(1.0 / sig[t]);
  }
  __syncthreads();
  for (int e = t; e < 4096; e += 256) {
    const int col = e >> 6, row = e & 63;
    double v = (S[row * 64 + col] - n * mu[row] * mu[col]) / (n * sig[row] * sig[col]);
    if (row == col) v += 1e-5;
    G[col * 68 + row] = (float)v;
  }
  __syncthreads();
  if (t < 64) {  // initial squared column norms
    float s = 0.0f;
#pragma unroll
    for (int j4 = 0; j4 < 16; ++j4) {
      const float4 v = *reinterpret_cast<const float4*>(G + t * 68 + (j4 << 2));
      s = fmaf(v.x, v.x, s); s = fmaf(v.y, v.y, s);
      s = fmaf(v.z, v.z, s); s = fmaf(v.w, v.w, s);
    }
    norms[t] = s;
  }
  __syncthreads();

  if (t < 64) {  // ---- single-wave Jacobi sweep loop, zero barriers ----
    const int g = t >> 1;
    const int o = (t & 1) << 5;  // 32 elements per lane
    for (int sweep = 0; sweep < 7; ++sweep) {
      int anyflag = 0;
      for (int r = 0; r < 63; ++r) {
        int p, q;
        zca_sched(g, r, p, q);
        float* Gp = G + p * 68 + o;
        float* Gq = G + q * 68 + o;
        float4 P[8], Q[8];
#pragma unroll
        for (int i = 0; i < 8; ++i) P[i] = *reinterpret_cast<float4*>(Gp + (i << 2));
#pragma unroll
        for (int i = 0; i < 8; ++i) Q[i] = *reinterpret_cast<float4*>(Gq + (i << 2));
        float s0 = 0.f, s1 = 0.f, s2 = 0.f, s3 = 0.f;
#pragma unroll
        for (int i = 0; i < 8; ++i) {
          s0 = fmaf(P[i].x, Q[i].x, s0);
          s1 = fmaf(P[i].y, Q[i].y, s1);
          s2 = fmaf(P[i].z, Q[i].z, s2);
          s3 = fmaf(P[i].w, Q[i].w, s3);
        }
        float apq = (s0 + s1) + (s2 + s3);
        apq += __shfl_xor(apq, 1);
        const float app = norms[p], aqq = norms[q];
        if (apq * apq > 1e-10f * app * aqq) {
          anyflag = 1;
          const float tau = (aqq - app) / (2.0f * apq);
          const float tt = (tau >= 0.0f ? 1.0f : -1.0f) / (fabsf(tau) + sqrtf(1.0f + tau * tau));
          const float c = 1.0f / sqrtf(1.0f + tt * tt);
          const float s = tt * c;
#pragma unroll
          for (int i = 0; i < 8; ++i) {
            float4 np, nq;
            np.x = c * P[i].x - s * Q[i].x; np.y = c * P[i].y - s * Q[i].y;
            np.z = c * P[i].z - s * Q[i].z; np.w = c * P[i].w - s * Q[i].w;
            nq.x = s * P[i].x + c * Q[i].x; nq.y = s * P[i].y + c * Q[i].y;
            nq.z = s * P[i].z + c * Q[i].z; nq.w = s * P[i].w + c * Q[i].w;
            *reinterpret_cast<float4*>(Gp + (i << 2)) = np;
            *reinterpret_cast<float4*>(Gq + (i << 2)) = nq;
          }
          // lane0 of pair owns norms[p] (-= tt*apq), lane1 owns norms[q]
          if ((t & 1) == 0) norms[p] = fmaf(-tt, apq, app);
          else              norms[q] = fmaf(tt, apq, aqq);
        }
        __builtin_amdgcn_wave_barrier();  // pin LDS program order across rounds
      }
      if (!__any(anyflag)) break;
    }
  }
  __syncthreads();

  // eigenvalues = exact column norms of converged G (G[:,i] = lam_i * v_i)
  if (t < 64) {
    float s = 0.0f;
#pragma unroll
    for (int j4 = 0; j4 < 16; ++j4) {
      const float4 v = *reinterpret_cast<const float4*>(G + t * 68 + (j4 << 2));
      s = fmaf(v.x, v.x, s); s = fmaf(v.y, v.y, s);
      s = fmaf(v.z, v.z, s); s = fmaf(v.w, v.w, s);
    }
    lam[t] = sqrtf(s);
  }
  __syncthreads();
  if (t < 64) {
    const float e = lam[t];
    int rank = 0;
    for (int j = 0; j < 64; ++j) {
      const float ej = lam[j];
      if (ej > e || (ej == e && j < t)) ++rank;
    }
    idxs[rank] = t;
  }
  __syncthreads();
  if (t == 0) {
    double total = 0.0;
    for (int j = 0; j < 64; ++j) total += (double)lam[j];
    double cum = 0.0;
    bool done = false;
    for (int k = 0; k < 64; ++k) {
      const double l = (double)lam[idxs[k]];
      cum += l;
      double w = 0.0;
      if (k < 32 && !done) w = 1.0 / (sqrt(l) * l * l);  // lam^(-1/2) / lam^2
      if (cum / total >= 0.95) done = true;
      wk2[k] = (float)w;
    }
  }
  __syncthreads();
  // Wxr[c][d] = sum_k wk2[k] * G[c,idx_k] * G[d,idx_k]; fold into T and off.
  {
    const int c = t >> 2, db = (t & 3) << 4;
    float accf[16];
#pragma unroll
    for (int d = 0; d < 16; ++d) accf[d] = 0.0f;
    for (int k = 0; k < 32; ++k) {
      const int sk = idxs[k];
      const float vc = wk2[k] * G[sk * 68 + c];
      const float* gcol = G + sk * 68 + db;
#pragma unroll
      for (int d4 = 0; d4 < 4; ++d4) {
        const float4 v = *reinterpret_cast<const float4*>(gcol + (d4 << 2));
        accf[d4 * 4 + 0] = fmaf(vc, v.x, accf[d4 * 4 + 0]);
        accf[d4 * 4 + 1] = fmaf(vc, v.y, accf[d4 * 4 + 1]);
        accf[d4 * 4 + 2] = fmaf(vc, v.z, accf[d4 * 4 + 2]);
        accf[d4 * 4 + 3] = fmaf(vc, v.w, accf[d4 * 4 + 3]);
      }
    }
    const float wc = weight[c];
    float po = 0.0f;
#pragma unroll
    for (int d = 0; d < 16; ++d) {
      T[c * 64 + db + d] = wc * accf[d] * isg[db + d];
      po = fmaf(accf[d], msd[db + d], po);
    }
    po += __shfl_xor(po, 1);
    po += __shfl_xor(po, 2);
    if ((t & 3) == 0) offv[c] = bias[c] - wc * po;
  }
}

// out[n,c,k] = sum_d T[c][d]*x[n,d,k] + off[c].
// Grid 512: (n = b>>3, 512 k per block, 2 positions per thread).
// T/off reads are loop-uniform -> scalar s_load path. UNCHANGED from r10.
__global__ __launch_bounds__(256) void zca_apply_k(const float* __restrict__ x,
                                                   const float* __restrict__ T,
                                                   const float* __restrict__ offv,
                                                   float* __restrict__ out) {
  const int t = threadIdx.x;
  const int n = blockIdx.x >> 3;
  const int k0 = ((blockIdx.x & 7) << 9) + (t << 1);
  const float* xb = x + ((size_t)n << 18) + k0;
  const float4* __restrict__ T4 = reinterpret_cast<const float4*>(T);
  float2 acc[64];
#pragma unroll
  for (int c = 0; c < 64; ++c) {
    const float o = offv[c];  // uniform -> s_load
    acc[c].x = o; acc[c].y = o;
  }
  float2 xv[4];
#pragma unroll
  for (int dd = 0; dd < 4; ++dd)
    xv[dd] = *reinterpret_cast<const float2*>(xb + ((size_t)dd << 12));
  for (int d4 = 0; d4 < 16; ++d4) {
    float2 xn[4];
    if (d4 < 15) {
#pragma unroll
      for (int dd = 0; dd < 4; ++dd)
        xn[dd] = *reinterpret_cast<const float2*>(xb + ((size_t)((d4 + 1) * 4 + dd) << 12));
    }
#pragma unroll
    for (int c = 0; c < 64; ++c) {
      const float4 tv = T4[(c << 4) + d4];  // uniform -> s_load_dwordx4
      acc[c].x = fmaf(tv.x, xv[0].x, acc[c].x); acc[c].y = fmaf(tv.x, xv[0].y, acc[c].y);
      acc[c].x = fmaf(tv.y, xv[1].x, acc[c].x); acc[c].y = fmaf(tv.y, xv[1].y, acc[c].y);
      acc[c].x = fmaf(tv.z, xv[2].x, acc[c].x); acc[c].y = fmaf(tv.z, xv[2].y, acc[c].y);
      acc[c].x = fmaf(tv.w, xv[3].x, acc[c].x); acc[c].y = fmaf(tv.w, xv[3].y, acc[c].y);
    }
#pragma unroll
    for (int dd = 0; dd < 4; ++dd) xv[dd] = xn[dd];
  }
  float* ob = out + ((size_t)n << 18) + k0;
#pragma unroll
  for (int c = 0; c < 64; ++c)
    *reinterpret_cast<float2*>(ob + ((size_t)c << 12)) = acc[c];
}

extern "C" void kernel_launch(void* const* d_in, const int* in_sizes, int n_in,
                              void* d_out, int out_size, void* d_ws, size_t ws_size,
                              hipStream_t stream) {
  const float* x = (const float*)d_in[0];
  const float* weight = (const float*)d_in[1];
  const float* bias = (const float*)d_in[2];
  float* out = (float*)d_out;
  char* ws = (char*)d_ws;
  double* S = (double*)ws;
  double* rowsum = (double*)(ws + 32768);
  float* T = (float*)(ws + 33280);
  float* offv = (float*)(ws + 49664);

  hipMemsetAsync(S, 0, 33280, stream);  // S + rowsum (graph-capturable)
  hipLaunchKernelGGL(zca_gram_k, dim3(256), dim3(256), 0, stream, x, S, rowsum);
  hipLaunchKernelGGL(zca_solve_k, dim3(1), dim3(256), 0, stream, S, rowsum, weight, bias, T, offv);
  hipLaunchKernelGGL(zca_apply_k, dim3(512), dim3(256), 0, stream, x, T, offv, out);
}

// Round 12
// 403.692 us; speedup vs baseline: 1.5122x; 1.1447x over previous
//
#include <hip/hip_runtime.h>

// Problem: N=C=H=W=64. n = N*H*W = 262144 samples per channel.
// ws layout:
//   [0,     32768)  S      double[64*64]   Gram accumulator
//   [32768, 33280)  rowsum double[64]
//   [33280, 49664)  T      float[64*64]    folded transform
//   [49664, 49920)  off    float[64]       folded offset

// Gram + row sums, v2: 8x8 register blocking. Grid 256. UNCHANGED from r11.
__global__ __launch_bounds__(256) void zca_gram_k(const float* __restrict__ x,
                                                  double* __restrict__ S,
                                                  double* __restrict__ rowsum) {
  __shared__ __align__(16) float buf[16384];  // phase1: XT[128][72]; phase2: 4x4096 partials
  __shared__ float rsbuf[256];
  const int t = threadIdx.x;
  const int n = blockIdx.x >> 2;
  const int k0base = (blockIdx.x & 3) << 10;
  const float* xb = x + ((size_t)n << 18);
  const int g = t >> 6;            // wave = k-group
  const int tt = t & 63;
  const int r0 = (tt >> 3) << 3;   // 8 output rows
  const int c0 = (tt & 7) << 3;    // 8 output cols

  float acc[8][8];
#pragma unroll
  for (int i = 0; i < 8; ++i)
#pragma unroll
    for (int j = 0; j < 8; ++j) acc[i][j] = 0.0f;
  float rs[8];
#pragma unroll
  for (int i = 0; i < 8; ++i) rs[i] = 0.0f;

  for (int tile = 0; tile < 8; ++tile) {
    const int k0 = k0base + (tile << 7);
#pragma unroll
    for (int r = 0; r < 8; ++r) {
      const int idx4 = t + (r << 8);
      const int c = idx4 >> 5;
      const int kk = (idx4 & 31) << 2;
      const float4 v = *reinterpret_cast<const float4*>(xb + ((size_t)c << 12) + k0 + kk);
      buf[(kk + 0) * 72 + c] = v.x;
      buf[(kk + 1) * 72 + c] = v.y;
      buf[(kk + 2) * 72 + c] = v.z;
      buf[(kk + 3) * 72 + c] = v.w;
    }
    __syncthreads();
    const int kbeg = g << 5;
#pragma unroll 2
    for (int kk = kbeg; kk < kbeg + 32; ++kk) {
      const float* row = buf + kk * 72;
      const float4 a0 = *reinterpret_cast<const float4*>(row + r0);
      const float4 a1 = *reinterpret_cast<const float4*>(row + r0 + 4);
      const float4 b0 = *reinterpret_cast<const float4*>(row + c0);
      const float4 b1 = *reinterpret_cast<const float4*>(row + c0 + 4);
      const float a[8] = {a0.x, a0.y, a0.z, a0.w, a1.x, a1.y, a1.z, a1.w};
      const float b[8] = {b0.x, b0.y, b0.z, b0.w, b1.x, b1.y, b1.z, b1.w};
#pragma unroll
      for (int i = 0; i < 8; ++i) {
#pragma unroll
        for (int j = 0; j < 8; ++j) acc[i][j] = fmaf(a[i], b[j], acc[i][j]);
        rs[i] += a[i];
      }
    }
    __syncthreads();
  }
#pragma unroll
  for (int i = 0; i < 8; ++i)
#pragma unroll
    for (int j = 0; j < 8; ++j)
      buf[(g << 12) + (r0 + i) * 64 + c0 + j] = acc[i][j];
  if ((tt & 7) == 0) {
#pragma unroll
    for (int i = 0; i < 8; ++i) rsbuf[(g << 6) + r0 + i] = rs[i];
  }
  __syncthreads();
  for (int e = t; e < 4096; e += 256) {
    const float s = (buf[e] + buf[4096 + e]) + (buf[8192 + e] + buf[12288 + e]);
    atomicAdd(&S[e], (double)s);
  }
  if (t < 64) {
    const float s = (rsbuf[t] + rsbuf[64 + t]) + (rsbuf[128 + t] + rsbuf[192 + t]);
    atomicAdd(&rowsum[t], (double)s);
  }
}

// round-robin tournament pairing: 32 disjoint pairs covering all 64 indices.
__device__ __forceinline__ void zca_sched(int j, int r, int& p, int& q) {
  if (j == 0) {
    p = 0;
    int a = 62 + r; if (a >= 63) a -= 63;
    q = 1 + a;
  } else {
    int a = j - 1 + r;  if (a >= 63) a -= 63;
    int b = 62 - j + r; if (b >= 63) b -= 63;
    p = 1 + a;
    q = 1 + b;
  }
}

// Single block. One-sided (Hestenes) Jacobi on columns of G = M0, f32,
// ONE WAVE (2 lanes/pair, 32 elems/lane), zero barriers in the loop.
// r12 change: sweep cap 7 -> 5, skip threshold back to 1e-11 (max
// rotations per sweep; skip never fires in practice so no time cost).
// Error model (r9 calibration): threshold contribution ~550*sqrt(rel);
// 7->6 sweeps contributed ~0; 5 is the probe point.
__global__ __launch_bounds__(256) void zca_solve_k(const double* __restrict__ S,
                                                   const double* __restrict__ rowsum,
                                                   const float* __restrict__ weight,
                                                   const float* __restrict__ bias,
                                                   float* __restrict__ T,
                                                   float* __restrict__ offv) {
  __shared__ __align__(16) float G[64 * 68];  // column-major, col stride 68
  __shared__ float norms[64];                 // running squared col norms
  __shared__ float lam[64];
  __shared__ float msd[64];                   // mu/sig (f32)
  __shared__ float isg[64];                   // 1/sig (f32)
  __shared__ double mu[64], sig[64];
  __shared__ float wk2[64];                   // active * lam^(-5/2)
  __shared__ int idxs[64];
  const int t = threadIdx.x;
  const double n = 262144.0;

  if (t < 64) {
    const double m = rowsum[t] / n;
    const double var = (S[t * 64 + t] - n * m * m) / (n - 1.0);
    mu[t] = m;
    sig[t] = sqrt(var + 1e-5);
    msd[t] = (float)(m / sig[t]);
    isg[t] = (float)(1.0 / sig[t]);
  }
  __syncthreads();
  for (int e = t; e < 4096; e += 256) {
    const int col = e >> 6, row = e & 63;
    double v = (S[row * 64 + col] - n * mu[row] * mu[col]) / (n * sig[row] * sig[col]);
    if (row == col) v += 1e-5;
    G[col * 68 + row] = (float)v;
  }
  __syncthreads();
  if (t < 64) {  // initial squared column norms
    float s = 0.0f;
#pragma unroll
    for (int j4 = 0; j4 < 16; ++j4) {
      const float4 v = *reinterpret_cast<const float4*>(G + t * 68 + (j4 << 2));
      s = fmaf(v.x, v.x, s); s = fmaf(v.y, v.y, s);
      s = fmaf(v.z, v.z, s); s = fmaf(v.w, v.w, s);
    }
    norms[t] = s;
  }
  __syncthreads();

  if (t < 64) {  // ---- single-wave Jacobi sweep loop, zero barriers ----
    const int g = t >> 1;
    const int o = (t & 1) << 5;  // 32 elements per lane
    for (int sweep = 0; sweep < 5; ++sweep) {
      int anyflag = 0;
      for (int r = 0; r < 63; ++r) {
        int p, q;
        zca_sched(g, r, p, q);
        float* Gp = G + p * 68 + o;
        float* Gq = G + q * 68 + o;
        float4 P[8], Q[8];
#pragma unroll
        for (int i = 0; i < 8; ++i) P[i] = *reinterpret_cast<float4*>(Gp + (i << 2));
#pragma unroll
        for (int i = 0; i < 8; ++i) Q[i] = *reinterpret_cast<float4*>(Gq + (i << 2));
        float s0 = 0.f, s1 = 0.f, s2 = 0.f, s3 = 0.f;
#pragma unroll
        for (int i = 0; i < 8; ++i) {
          s0 = fmaf(P[i].x, Q[i].x, s0);
          s1 = fmaf(P[i].y, Q[i].y, s1);
          s2 = fmaf(P[i].z, Q[i].z, s2);
          s3 = fmaf(P[i].w, Q[i].w, s3);
        }
        float apq = (s0 + s1) + (s2 + s3);
        apq += __shfl_xor(apq, 1);
        const float app = norms[p], aqq = norms[q];
        if (apq * apq > 1e-11f * app * aqq) {
          anyflag = 1;
          const float tau = (aqq - app) / (2.0f * apq);
          const float tt = (tau >= 0.0f ? 1.0f : -1.0f) / (fabsf(tau) + sqrtf(1.0f + tau * tau));
          const float c = 1.0f / sqrtf(1.0f + tt * tt);
          const float s = tt * c;
#pragma unroll
          for (int i = 0; i < 8; ++i) {
            float4 np, nq;
            np.x = c * P[i].x - s * Q[i].x; np.y = c * P[i].y - s * Q[i].y;
            np.z = c * P[i].z - s * Q[i].z; np.w = c * P[i].w - s * Q[i].w;
            nq.x = s * P[i].x + c * Q[i].x; nq.y = s * P[i].y + c * Q[i].y;
            nq.z = s * P[i].z + c * Q[i].z; nq.w = s * P[i].w + c * Q[i].w;
            *reinterpret_cast<float4*>(Gp + (i << 2)) = np;
            *reinterpret_cast<float4*>(Gq + (i << 2)) = nq;
          }
          // lane0 of pair owns norms[p] (-= tt*apq), lane1 owns norms[q]
          if ((t & 1) == 0) norms[p] = fmaf(-tt, apq, app);
          else              norms[q] = fmaf(tt, apq, aqq);
        }
        __builtin_amdgcn_wave_barrier();  // pin LDS program order across rounds
      }
      if (!__any(anyflag)) break;
    }
  }
  __syncthreads();

  // eigenvalues = exact column norms of converged G (G[:,i] = lam_i * v_i)
  if (t < 64) {
    float s = 0.0f;
#pragma unroll
    for (int j4 = 0; j4 < 16; ++j4) {
      const float4 v = *reinterpret_cast<const float4*>(G + t * 68 + (j4 << 2));
      s = fmaf(v.x, v.x, s); s = fmaf(v.y, v.y, s);
      s = fmaf(v.z, v.z, s); s = fmaf(v.w, v.w, s);
    }
    lam[t] = sqrtf(s);
  }
  __syncthreads();
  if (t < 64) {
    const float e = lam[t];
    int rank = 0;
    for (int j = 0; j < 64; ++j) {
      const float ej = lam[j];
      if (ej > e || (ej == e && j < t)) ++rank;
    }
    idxs[rank] = t;
  }
  __syncthreads();
  if (t == 0) {
    double total = 0.0;
    for (int j = 0; j < 64; ++j) total += (double)lam[j];
    double cum = 0.0;
    bool done = false;
    for (int k = 0; k < 64; ++k) {
      const double l = (double)lam[idxs[k]];
      cum += l;
      double w = 0.0;
      if (k < 32 && !done) w = 1.0 / (sqrt(l) * l * l);  // lam^(-1/2) / lam^2
      if (cum / total >= 0.95) done = true;
      wk2[k] = (float)w;
    }
  }
  __syncthreads();
  // Wxr[c][d] = sum_k wk2[k] * G[c,idx_k] * G[d,idx_k]; fold into T and off.
  {
    const int c = t >> 2, db = (t & 3) << 4;
    float accf[16];
#pragma unroll
    for (int d = 0; d < 16; ++d) accf[d] = 0.0f;
    for (int k = 0; k < 32; ++k) {
      const int sk = idxs[k];
      const float vc = wk2[k] * G[sk * 68 + c];
      const float* gcol = G + sk * 68 + db;
#pragma unroll
      for (int d4 = 0; d4 < 4; ++d4) {
        const float4 v = *reinterpret_cast<const float4*>(gcol + (d4 << 2));
        accf[d4 * 4 + 0] = fmaf(vc, v.x, accf[d4 * 4 + 0]);
        accf[d4 * 4 + 1] = fmaf(vc, v.y, accf[d4 * 4 + 1]);
        accf[d4 * 4 + 2] = fmaf(vc, v.z, accf[d4 * 4 + 2]);
        accf[d4 * 4 + 3] = fmaf(vc, v.w, accf[d4 * 4 + 3]);
      }
    }
    const float wc = weight[c];
    float po = 0.0f;
#pragma unroll
    for (int d = 0; d < 16; ++d) {
      T[c * 64 + db + d] = wc * accf[d] * isg[db + d];
      po = fmaf(accf[d], msd[db + d], po);
    }
    po += __shfl_xor(po, 1);
    po += __shfl_xor(po, 2);
    if ((t & 3) == 0) offv[c] = bias[c] - wc * po;
  }
}

// out[n,c,k] = sum_d T[c][d]*x[n,d,k] + off[c].
// Grid 512: T/off via uniform s_load path. UNCHANGED from r10/r11.
__global__ __launch_bounds__(256) void zca_apply_k(const float* __restrict__ x,
                                                   const float* __restrict__ T,
                                                   const float* __restrict__ offv,
                                                   float* __restrict__ out) {
  const int t = threadIdx.x;
  const int n = blockIdx.x >> 3;
  const int k0 = ((blockIdx.x & 7) << 9) + (t << 1);
  const float* xb = x + ((size_t)n << 18) + k0;
  const float4* __restrict__ T4 = reinterpret_cast<const float4*>(T);
  float2 acc[64];
#pragma unroll
  for (int c = 0; c < 64; ++c) {
    const float o = offv[c];  // uniform -> s_load
    acc[c].x = o; acc[c].y = o;
  }
  float2 xv[4];
#pragma unroll
  for (int dd = 0; dd < 4; ++dd)
    xv[dd] = *reinterpret_cast<const float2*>(xb + ((size_t)dd << 12));
  for (int d4 = 0; d4 < 16; ++d4) {
    float2 xn[4];
    if (d4 < 15) {
#pragma unroll
      for (int dd = 0; dd < 4; ++dd)
        xn[dd] = *reinterpret_cast<const float2*>(xb + ((size_t)((d4 + 1) * 4 + dd) << 12));
    }
#pragma unroll
    for (int c = 0; c < 64; ++c) {
      const float4 tv = T4[(c << 4) + d4];  // uniform -> s_load_dwordx4
      acc[c].x = fmaf(tv.x, xv[0].x, acc[c].x); acc[c].y = fmaf(tv.x, xv[0].y, acc[c].y);
      acc[c].x = fmaf(tv.y, xv[1].x, acc[c].x); acc[c].y = fmaf(tv.y, xv[1].y, acc[c].y);
      acc[c].x = fmaf(tv.z, xv[2].x, acc[c].x); acc[c].y = fmaf(tv.z, xv[2].y, acc[c].y);
      acc[c].x = fmaf(tv.w, xv[3].x, acc[c].x); acc[c].y = fmaf(tv.w, xv[3].y, acc[c].y);
    }
#pragma unroll
    for (int dd = 0; dd < 4; ++dd) xv[dd] = xn[dd];
  }
  float* ob = out + ((size_t)n << 18) + k0;
#pragma unroll
  for (int c = 0; c < 64; ++c)
    *reinterpret_cast<float2*>(ob + ((size_t)c << 12)) = acc[c];
}

extern "C" void kernel_launch(void* const* d_in, const int* in_sizes, int n_in,
                              void* d_out, int out_size, void* d_ws, size_t ws_size,
                              hipStream_t stream) {
  const float* x = (const float*)d_in[0];
  const float* weight = (const float*)d_in[1];
  const float* bias = (const float*)d_in[2];
  float* out = (float*)d_out;
  char* ws = (char*)d_ws;
  double* S = (double*)ws;
  double* rowsum = (double*)(ws + 32768);
  float* T = (float*)(ws + 33280);
  float* offv = (float*)(ws + 49664);

  hipMemsetAsync(S, 0, 33280, stream);  // S + rowsum (graph-capturable)
  hipLaunchKernelGGL(zca_gram_k, dim3(256), dim3(256), 0, stream, x, S, rowsum);
  hipLaunchKernelGGL(zca_solve_k, dim3(1), dim3(256), 0, stream, S, rowsum, weight, bias, T, offv);
  hipLaunchKernelGGL(zca_apply_k, dim3(512), dim3(256), 0, stream, x, T, offv, out);
}

// Round 14
// 402.658 us; speedup vs baseline: 1.5161x; 1.0026x over previous
//
#include <hip/hip_runtime.h>

// Problem: N=C=H=W=64. n = N*H*W = 262144 samples per channel.
// ws layout:
//   [0,     32768)  S      double[64*64]   Gram accumulator
//   [32768, 33280)  rowsum double[64]
//   [33280, 49664)  T      float[64*64]    folded transform
//   [49664, 49920)  off    float[64]       folded offset
//
// FINAL CONFIG (= r12, measured PASS 404us, absmax 0.0176):
//  - gram: 8x8 register blocking, grid 256 (r11)
//  - solve: single-wave Hestenes Jacobi, 5 sweeps (r13 proved 4 fails),
//    skip threshold 1e-11 (r9 proved 1e-8 fails)
//  - apply: float2 x 2 positions, uniform s_load T (r10)

// Gram + row sums, v2: 8x8 register blocking. Grid 256.
__global__ __launch_bounds__(256) void zca_gram_k(const float* __restrict__ x,
                                                  double* __restrict__ S,
                                                  double* __restrict__ rowsum) {
  __shared__ __align__(16) float buf[16384];  // phase1: XT[128][72]; phase2: 4x4096 partials
  __shared__ float rsbuf[256];
  const int t = threadIdx.x;
  const int n = blockIdx.x >> 2;
  const int k0base = (blockIdx.x & 3) << 10;
  const float* xb = x + ((size_t)n << 18);
  const int g = t >> 6;            // wave = k-group
  const int tt = t & 63;
  const int r0 = (tt >> 3) << 3;   // 8 output rows
  const int c0 = (tt & 7) << 3;    // 8 output cols

  float acc[8][8];
#pragma unroll
  for (int i = 0; i < 8; ++i)
#pragma unroll
    for (int j = 0; j < 8; ++j) acc[i][j] = 0.0f;
  float rs[8];
#pragma unroll
  for (int i = 0; i < 8; ++i) rs[i] = 0.0f;

  for (int tile = 0; tile < 8; ++tile) {
    const int k0 = k0base + (tile << 7);
#pragma unroll
    for (int r = 0; r < 8; ++r) {
      const int idx4 = t + (r << 8);
      const int c = idx4 >> 5;
      const int kk = (idx4 & 31) << 2;
      const float4 v = *reinterpret_cast<const float4*>(xb + ((size_t)c << 12) + k0 + kk);
      buf[(kk + 0) * 72 + c] = v.x;
      buf[(kk + 1) * 72 + c] = v.y;
      buf[(kk + 2) * 72 + c] = v.z;
      buf[(kk + 3) * 72 + c] = v.w;
    }
    __syncthreads();
    const int kbeg = g << 5;
#pragma unroll 2
    for (int kk = kbeg; kk < kbeg + 32; ++kk) {
      const float* row = buf + kk * 72;
      const float4 a0 = *reinterpret_cast<const float4*>(row + r0);
      const float4 a1 = *reinterpret_cast<const float4*>(row + r0 + 4);
      const float4 b0 = *reinterpret_cast<const float4*>(row + c0);
      const float4 b1 = *reinterpret_cast<const float4*>(row + c0 + 4);
      const float a[8] = {a0.x, a0.y, a0.z, a0.w, a1.x, a1.y, a1.z, a1.w};
      const float b[8] = {b0.x, b0.y, b0.z, b0.w, b1.x, b1.y, b1.z, b1.w};
#pragma unroll
      for (int i = 0; i < 8; ++i) {
#pragma unroll
        for (int j = 0; j < 8; ++j) acc[i][j] = fmaf(a[i], b[j], acc[i][j]);
        rs[i] += a[i];
      }
    }
    __syncthreads();
  }
#pragma unroll
  for (int i = 0; i < 8; ++i)
#pragma unroll
    for (int j = 0; j < 8; ++j)
      buf[(g << 12) + (r0 + i) * 64 + c0 + j] = acc[i][j];
  if ((tt & 7) == 0) {
#pragma unroll
    for (int i = 0; i < 8; ++i) rsbuf[(g << 6) + r0 + i] = rs[i];
  }
  __syncthreads();
  for (int e = t; e < 4096; e += 256) {
    const float s = (buf[e] + buf[4096 + e]) + (buf[8192 + e] + buf[12288 + e]);
    atomicAdd(&S[e], (double)s);
  }
  if (t < 64) {
    const float s = (rsbuf[t] + rsbuf[64 + t]) + (rsbuf[128 + t] + rsbuf[192 + t]);
    atomicAdd(&rowsum[t], (double)s);
  }
}

// round-robin tournament pairing: 32 disjoint pairs covering all 64 indices.
__device__ __forceinline__ void zca_sched(int j, int r, int& p, int& q) {
  if (j == 0) {
    p = 0;
    int a = 62 + r; if (a >= 63) a -= 63;
    q = 1 + a;
  } else {
    int a = j - 1 + r;  if (a >= 63) a -= 63;
    int b = 62 - j + r; if (b >= 63) b -= 63;
    p = 1 + a;
    q = 1 + b;
  }
}

// Single block. One-sided (Hestenes) Jacobi on columns of G = M0, f32,
// ONE WAVE (2 lanes/pair, 32 elems/lane), zero barriers in the loop.
// 5 sweeps (validated minimum: 4 -> absmax 0.172 FAIL, 5 -> 0.0176 PASS),
// skip threshold 1e-11 rel (1e-8 -> FAIL at 0.070).
__global__ __launch_bounds__(256) void zca_solve_k(const double* __restrict__ S,
                                                   const double* __restrict__ rowsum,
                                                   const float* __restrict__ weight,
                                                   const float* __restrict__ bias,
                                                   float* __restrict__ T,
                                                   float* __restrict__ offv) {
  __shared__ __align__(16) float G[64 * 68];  // column-major, col stride 68
  __shared__ float norms[64];                 // running squared col norms
  __shared__ float lam[64];
  __shared__ float msd[64];                   // mu/sig (f32)
  __shared__ float isg[64];                   // 1/sig (f32)
  __shared__ double mu[64], sig[64];
  __shared__ float wk2[64];                   // active * lam^(-5/2)
  __shared__ int idxs[64];
  const int t = threadIdx.x;
  const double n = 262144.0;

  if (t < 64) {
    const double m = rowsum[t] / n;
    const double var = (S[t * 64 + t] - n * m * m) / (n - 1.0);
    mu[t] = m;
    sig[t] = sqrt(var + 1e-5);
    msd[t] = (float)(m / sig[t]);
    isg[t] = (float)(1.0 / sig[t]);
  }
  __syncthreads();
  for (int e = t; e < 4096; e += 256) {
    const int col = e >> 6, row = e & 63;
    double v = (S[row * 64 + col] - n * mu[row] * mu[col]) / (n * sig[row] * sig[col]);
    if (row == col) v += 1e-5;
    G[col * 68 + row] = (float)v;
  }
  __syncthreads();
  if (t < 64) {  // initial squared column norms
    float s = 0.0f;
#pragma unroll
    for (int j4 = 0; j4 < 16; ++j4) {
      const float4 v = *reinterpret_cast<const float4*>(G + t * 68 + (j4 << 2));
      s = fmaf(v.x, v.x, s); s = fmaf(v.y, v.y, s);
      s = fmaf(v.z, v.z, s); s = fmaf(v.w, v.w, s);
    }
    norms[t] = s;
  }
  __syncthreads();

  if (t < 64) {  // ---- single-wave Jacobi sweep loop, zero barriers ----
    const int g = t >> 1;
    const int o = (t & 1) << 5;  // 32 elements per lane
    for (int sweep = 0; sweep < 5; ++sweep) {
      int anyflag = 0;
      for (int r = 0; r < 63; ++r) {
        int p, q;
        zca_sched(g, r, p, q);
        float* Gp = G + p * 68 + o;
        float* Gq = G + q * 68 + o;
        float4 P[8], Q[8];
#pragma unroll
        for (int i = 0; i < 8; ++i) P[i] = *reinterpret_cast<float4*>(Gp + (i << 2));
#pragma unroll
        for (int i = 0; i < 8; ++i) Q[i] = *reinterpret_cast<float4*>(Gq + (i << 2));
        float s0 = 0.f, s1 = 0.f, s2 = 0.f, s3 = 0.f;
#pragma unroll
        for (int i = 0; i < 8; ++i) {
          s0 = fmaf(P[i].x, Q[i].x, s0);
          s1 = fmaf(P[i].y, Q[i].y, s1);
          s2 = fmaf(P[i].z, Q[i].z, s2);
          s3 = fmaf(P[i].w, Q[i].w, s3);
        }
        float apq = (s0 + s1) + (s2 + s3);
        apq += __shfl_xor(apq, 1);
        const float app = norms[p], aqq = norms[q];
        if (apq * apq > 1e-11f * app * aqq) {
          anyflag = 1;
          const float tau = (aqq - app) / (2.0f * apq);
          const float tt = (tau >= 0.0f ? 1.0f : -1.0f) / (fabsf(tau) + sqrtf(1.0f + tau * tau));
          const float c = 1.0f / sqrtf(1.0f + tt * tt);
          const float s = tt * c;
#pragma unroll
          for (int i = 0; i < 8; ++i) {
            float4 np, nq;
            np.x = c * P[i].x - s * Q[i].x; np.y = c * P[i].y - s * Q[i].y;
            np.z = c * P[i].z - s * Q[i].z; np.w = c * P[i].w - s * Q[i].w;
            nq.x = s * P[i].x + c * Q[i].x; nq.y = s * P[i].y + c * Q[i].y;
            nq.z = s * P[i].z + c * Q[i].z; nq.w = s * P[i].w + c * Q[i].w;
            *reinterpret_cast<float4*>(Gp + (i << 2)) = np;
            *reinterpret_cast<float4*>(Gq + (i << 2)) = nq;
          }
          // lane0 of pair owns norms[p] (-= tt*apq), lane1 owns norms[q]
          if ((t & 1) == 0) norms[p] = fmaf(-tt, apq, app);
          else              norms[q] = fmaf(tt, apq, aqq);
        }
        __builtin_amdgcn_wave_barrier();  // pin LDS program order across rounds
      }
      if (!__any(anyflag)) break;
    }
  }
  __syncthreads();

  // eigenvalues = exact column norms of converged G (G[:,i] = lam_i * v_i)
  if (t < 64) {
    float s = 0.0f;
#pragma unroll
    for (int j4 = 0; j4 < 16; ++j4) {
      const float4 v = *reinterpret_cast<const float4*>(G + t * 68 + (j4 << 2));
      s = fmaf(v.x, v.x, s); s = fmaf(v.y, v.y, s);
      s = fmaf(v.z, v.z, s); s = fmaf(v.w, v.w, s);
    }
    lam[t] = sqrtf(s);
  }
  __syncthreads();
  if (t < 64) {
    const float e = lam[t];
    int rank = 0;
    for (int j = 0; j < 64; ++j) {
      const float ej = lam[j];
      if (ej > e || (ej == e && j < t)) ++rank;
    }
    idxs[rank] = t;
  }
  __syncthreads();
  if (t == 0) {
    double total = 0.0;
    for (int j = 0; j < 64; ++j) total += (double)lam[j];
    double cum = 0.0;
    bool done = false;
    for (int k = 0; k < 64; ++k) {
      const double l = (double)lam[idxs[k]];
      cum += l;
      double w = 0.0;
      if (k < 32 && !done) w = 1.0 / (sqrt(l) * l * l);  // lam^(-1/2) / lam^2
      if (cum / total >= 0.95) done = true;
      wk2[k] = (float)w;
    }
  }
  __syncthreads();
  // Wxr[c][d] = sum_k wk2[k] * G[c,idx_k] * G[d,idx_k]; fold into T and off.
  {
    const int c = t >> 2, db = (t & 3) << 4;
    float accf[16];
#pragma unroll
    for (int d = 0; d < 16; ++d) accf[d] = 0.0f;
    for (int k = 0; k < 32; ++k) {
      const int sk = idxs[k];
      const float vc = wk2[k] * G[sk * 68 + c];
      const float* gcol = G + sk * 68 + db;
#pragma unroll
      for (int d4 = 0; d4 < 4; ++d4) {
        const float4 v = *reinterpret_cast<const float4*>(gcol + (d4 << 2));
        accf[d4 * 4 + 0] = fmaf(vc, v.x, accf[d4 * 4 + 0]);
        accf[d4 * 4 + 1] = fmaf(vc, v.y, accf[d4 * 4 + 1]);
        accf[d4 * 4 + 2] = fmaf(vc, v.z, accf[d4 * 4 + 2]);
        accf[d4 * 4 + 3] = fmaf(vc, v.w, accf[d4 * 4 + 3]);
      }
    }
    const float wc = weight[c];
    float po = 0.0f;
#pragma unroll
    for (int d = 0; d < 16; ++d) {
      T[c * 64 + db + d] = wc * accf[d] * isg[db + d];
      po = fmaf(accf[d], msd[db + d], po);
    }
    po += __shfl_xor(po, 1);
    po += __shfl_xor(po, 2);
    if ((t & 3) == 0) offv[c] = bias[c] - wc * po;
  }
}

// out[n,c,k] = sum_d T[c][d]*x[n,d,k] + off[c].
// Grid 512: T/off via uniform s_load path.
__global__ __launch_bounds__(256) void zca_apply_k(const float* __restrict__ x,
                                                   const float* __restrict__ T,
                                                   const float* __restrict__ offv,
                                                   float* __restrict__ out) {
  const int t = threadIdx.x;
  const int n = blockIdx.x >> 3;
  const int k0 = ((blockIdx.x & 7) << 9) + (t << 1);
  const float* xb = x + ((size_t)n << 18) + k0;
  const float4* __restrict__ T4 = reinterpret_cast<const float4*>(T);
  float2 acc[64];
#pragma unroll
  for (int c = 0; c < 64; ++c) {
    const float o = offv[c];  // uniform -> s_load
    acc[c].x = o; acc[c].y = o;
  }
  float2 xv[4];
#pragma unroll
  for (int dd = 0; dd < 4; ++dd)
    xv[dd] = *reinterpret_cast<const float2*>(xb + ((size_t)dd << 12));
  for (int d4 = 0; d4 < 16; ++d4) {
    float2 xn[4];
    if (d4 < 15) {
#pragma unroll
      for (int dd = 0; dd < 4; ++dd)
        xn[dd] = *reinterpret_cast<const float2*>(xb + ((size_t)((d4 + 1) * 4 + dd) << 12));
    }
#pragma unroll
    for (int c = 0; c < 64; ++c) {
      const float4 tv = T4[(c << 4) + d4];  // uniform -> s_load_dwordx4
      acc[c].x = fmaf(tv.x, xv[0].x, acc[c].x); acc[c].y = fmaf(tv.x, xv[0].y, acc[c].y);
      acc[c].x = fmaf(tv.y, xv[1].x, acc[c].x); acc[c].y = fmaf(tv.y, xv[1].y, acc[c].y);
      acc[c].x = fmaf(tv.z, xv[2].x, acc[c].x); acc[c].y = fmaf(tv.z, xv[2].y, acc[c].y);
      acc[c].x = fmaf(tv.w, xv[3].x, acc[c].x); acc[c].y = fmaf(tv.w, xv[3].y, acc[c].y);
    }
#pragma unroll
    for (int dd = 0; dd < 4; ++dd) xv[dd] = xn[dd];
  }
  float* ob = out + ((size_t)n << 18) + k0;
#pragma unroll
  for (int c = 0; c < 64; ++c)
    *reinterpret_cast<float2*>(ob + ((size_t)c << 12)) = acc[c];
}

extern "C" void kernel_launch(void* const* d_in, const int* in_sizes, int n_in,
                              void* d_out, int out_size, void* d_ws, size_t ws_size,
                              hipStream_t stream) {
  const float* x = (const float*)d_in[0];
  const float* weight = (const float*)d_in[1];
  const float* bias = (const float*)d_in[2];
  float* out = (float*)d_out;
  char* ws = (char*)d_ws;
  double* S = (double*)ws;
  double* rowsum = (double*)(ws + 32768);
  float* T = (float*)(ws + 33280);
  float* offv = (float*)(ws + 49664);

  hipMemsetAsync(S, 0, 33280, stream);  // S + rowsum (graph-capturable)
  hipLaunchKernelGGL(zca_gram_k, dim3(256), dim3(256), 0, stream, x, S, rowsum);
  hipLaunchKernelGGL(zca_solve_k, dim3(1), dim3(256), 0, stream, S, rowsum, weight, bias, T, offv);
  hipLaunchKernelGGL(zca_apply_k, dim3(512), dim3(256), 0, stream, x, T, offv, out);
}